// Round 7
// baseline (68.825 us; speedup 1.0000x reference)
//
#include <hip/hip_runtime.h>
#include <hip/hip_bf16.h>

typedef unsigned int u32;
typedef unsigned short u16;
typedef float f32x4 __attribute__((ext_vector_type(4)));
typedef short s16x8 __attribute__((ext_vector_type(8)));

#define B_   2
#define S_   2048
#define HID_ 512
#define H_   8
#define HKV_ 2
#define QB_  8
#define VB_  16
#define NQ_  64
#define HVB_ 128
#define SCALE_ 0.0625f
#define MFIX_  17.0f

__device__ __forceinline__ u16 f2bf(float f) {
    u32 b = __builtin_bit_cast(u32, f);
    b += 0x7FFFu + ((b >> 16) & 1u);
    return (u16)(b >> 16);
}
__device__ __forceinline__ float bf2f(u16 h) {
    u32 b = ((u32)h) << 16;
    return __builtin_bit_cast(float, b);
}
__device__ __forceinline__ f32x4 mfma16(s16x8 a, s16x8 b, f32x4 c) {
    return __builtin_amdgcn_mfma_f32_16x16x32_bf16(a, b, c, 0, 0, 0);
}
// NaN-free by range analysis: e in [0,inf] -> rcp in [0,1] -> result in [-1,1].
__device__ __forceinline__ float fast_tanh(float x) {
    float e = __expf(2.f * x);
    return 1.f - 2.f * __builtin_amdgcn_rcpf(e + 1.f);
}
__device__ __forceinline__ float fast_sigmoid(float x) {
    return __builtin_amdgcn_rcpf(1.f + __expf(-x));
}

// ------------------------------------------------- K0: weights -> single bf16 planes
// Wc [128][512] row-major (rows 112..127 zero-padded); Wob [512][128] row-major.
__global__ void k0_convert(const float* __restrict__ Wq, const float* __restrict__ Wk,
                           const float* __restrict__ Wv, const float* __restrict__ Wo,
                           u16* __restrict__ Wc, u16* __restrict__ Wob) {
    int idx = blockIdx.x * 256 + threadIdx.x;          // grid 256 -> 65536 threads
    {
        int n = idx >> 9, k = idx & 511;
        float v = (n < NQ_) ? Wq[n * HID_ + k]
                : (n < NQ_ + 16) ? Wk[(n - NQ_) * HID_ + k]
                : (n < 112) ? Wv[(n - NQ_ - 16) * HID_ + k] : 0.f;
        Wc[idx] = f2bf(v);                             // idx == n*512 + k
    }
    Wob[idx] = f2bf(Wo[idx]);                          // 512*128 == 65536
}

// ------------------------------------------------- K1: projections (single bf16, no LDS)
// grid 256 (16 rows), block 256 (4 waves); wave wv owns n-frags {wv, wv+4}.
// A-frags converted f32->bf16 in-register; B-frags direct from Wc (L2).
__global__ __launch_bounds__(256) void k1_proj(
    const float* __restrict__ hidden, const u16* __restrict__ Wc,
    u16* __restrict__ qb, u16* __restrict__ kb, u16* __restrict__ vt)
{
    const int tid = threadIdx.x;
    const int r0 = blockIdx.x * 16;
    const int wv = tid >> 6, lane = tid & 63;
    const int li = lane & 15, lo4 = lane >> 4;

    const float* hrow = hidden + (r0 + li) * HID_;

    f32x4 acc[2];
    acc[0] = (f32x4){0.f, 0.f, 0.f, 0.f};
    acc[1] = (f32x4){0.f, 0.f, 0.f, 0.f};

    #pragma unroll
    for (int kc = 0; kc < 16; ++kc) {
        f32x4 x0 = *(const f32x4*)&hrow[32 * kc + 8 * lo4];
        f32x4 x1 = *(const f32x4*)&hrow[32 * kc + 8 * lo4 + 4];
        s16x8 a = { (short)f2bf(x0[0]), (short)f2bf(x0[1]), (short)f2bf(x0[2]), (short)f2bf(x0[3]),
                    (short)f2bf(x1[0]), (short)f2bf(x1[1]), (short)f2bf(x1[2]), (short)f2bf(x1[3]) };
        #pragma unroll
        for (int u = 0; u < 2; ++u) {
            int n = (wv + 4 * u) * 16 + li;
            s16x8 bfr = *(const s16x8*)&Wc[n * HID_ + 32 * kc + 8 * lo4];
            acc[u] = mfma16(a, bfr, acc[u]);
        }
    }

    #pragma unroll
    for (int u = 0; u < 2; ++u) {
        int n = (wv + 4 * u) * 16 + li;
        if (n < 112) {
            #pragma unroll
            for (int reg = 0; reg < 4; ++reg) {
                int gs = r0 + 4 * lo4 + reg;
                int b = gs >> 11, s = gs & 2047;
                float pre = acc[u][reg];
                if (n < NQ_) {
                    int h = n >> 3, bit = n & 7;
                    qb[(((b * H_ + h) * S_) + s) * QB_ + bit] = f2bf(fast_tanh(pre));
                } else if (n < NQ_ + 16) {
                    int nk = n - NQ_;
                    kb[(((b * HKV_ + (nk >> 3)) * S_) + s) * QB_ + (nk & 7)] = f2bf(fast_tanh(pre));
                } else {
                    int nv = n - NQ_ - 16;
                    int hv = nv >> 4, vb = nv & 15;
                    u16 sig = f2bf(fast_sigmoid(pre));
                    if (s > 0)
                        vt[((b * HKV_ + hv) * VB_ + vb) * S_ + (s - 1)] = sig;   // suffix shift
                    if (s == S_ - 1)
                        vt[((b * HKV_ + hv) * VB_ + vb) * S_ + (S_ - 1)] = 0;
                }
            }
        }
    }
}

// ------------------------------------------------- K2: fused windowed attention
// grid 512 = 32 row-blocks x 16 bh; block 256 = 2 row-waves(32 i each, 2 ig) x 2 J-groups.
// Each dedup'd K-fragment LDS read now feeds 4 MFMAs (2 ig x 2 kk) -> LDS traffic halved.
__global__ __launch_bounds__(256, 2) void k2_attn(
    const u16* __restrict__ qb, const u16* __restrict__ kb, const u16* __restrict__ vt,
    const float* __restrict__ vemb0, const float* __restrict__ vemb1,
    u16* __restrict__ AO)
{
    __shared__ __align__(16) u16 ks[2][2][96 * 8];     // [group][dbuf][rows]
    __shared__ __align__(16) u16 psa[4][32 * 72];      // per-wave P (32 i-rows)
    __shared__ __align__(16) float Om[4][2][16][17];
    __shared__ float lv[4][2][16];

    const int tid = threadIdx.x;
    const int bid = blockIdx.x;
    const int rb = bid >> 4;
    const int r  = (rb < 16) ? (31 - rb) : (rb - 16);  // complementary heavy/light pairing
    const int I0 = r * 64;
    const int nJ = r + 1;
    const int bh = bid & 15;
    const int b = bh >> 3, h = bh & 7, hkv = h >> 2;

    const int qhb = ((b * H_ + h) * S_) * QB_;
    const int khb = ((b * HKV_ + hkv) * S_) * QB_;
    const int vhb = ((b * HKV_ + hkv) * VB_) * S_;

    const int w = tid >> 6, lane = tid & 63;
    const int rw = w & 1, g = w >> 1;
    const int li = lane & 15, lo4 = lane >> 4;
    const int tloc = tid & 127;                        // per-group thread id (128 thr/group)

    u16* psw = psa[w];

    // hoist Q A-frags for both ig sub-tiles (A rows indexed by li)
    s16x8 qf[2][8];
    #pragma unroll
    for (int ig = 0; ig < 2; ++ig) {
        const int gr0 = I0 + 32 * rw + 16 * ig + li - 31 + lo4;
        const u16* qp = qb + qhb + gr0 * QB_;
        #pragma unroll
        for (int kk = 0; kk < 8; ++kk) {
            s16x8 v = {0, 0, 0, 0, 0, 0, 0, 0};
            if (gr0 + 4 * kk >= 0) v = *(const s16x8*)(qp + kk * 32);
            qf[ig][kk] = v;
        }
    }

    // bias reciprocals for the 8 output rows this lane owns (rows via 4*lo4+reg)
    float binv[2][4];
    #pragma unroll
    for (int ig = 0; ig < 2; ++ig)
        #pragma unroll
        for (int reg = 0; reg < 4; ++reg) {
            float d = (float)(I0 + 32 * rw + 16 * ig + 4 * lo4 + reg + 1);
            float rc = __builtin_amdgcn_rcpf(d);
            binv[ig][reg] = rc * (2.f - d * rc);       // one NR step: f32-exact here
        }

    f32x4 O[2];
    O[0] = (f32x4){0.f, 0.f, 0.f, 0.f};
    O[1] = (f32x4){0.f, 0.f, 0.f, 0.f};
    float lsum[2][4] = {{0.f, 0.f, 0.f, 0.f}, {0.f, 0.f, 0.f, 0.f}};

    const u16* vtp = vt + vhb + li * S_ + 8 * lo4;

    // prologue: stage tile jt = g into buf 0 (rows actually read: tloc 0..94)
    if (g < nJ && tloc < 95) {
        int gr = 64 * g - 31 + tloc;
        s16x8 v = {0, 0, 0, 0, 0, 0, 0, 0};
        if (gr >= 0) v = *(const s16x8*)(kb + khb + gr * QB_);
        *(s16x8*)&ks[g][0][tloc * 8] = v;
    }
    __syncthreads();

    const int nT = (nJ + 1) >> 1;
    for (int t = 0; t < nT; ++t) {
        const int cb = t & 1;
        const int jt = 2 * t + g;

        // T14 split: issue next-tile global load EARLY, ds_write LATE
        const bool do_stage = ((jt + 2) < nJ) && (tloc < 95);
        s16x8 stg;
        if (do_stage)
            stg = *(const s16x8*)(kb + khb + (64 * (jt + 2) - 31 + tloc) * QB_);

        if (jt < nJ) {
            // QK^T, implicit window-unfold (K=256), 20 dedup'd reads -> 64 MFMAs
            const u16* kbuf = &ks[g][cb][(li + lo4) * 8];
            f32x4 sacc[2][4];
            #pragma unroll
            for (int ig = 0; ig < 2; ++ig)
                #pragma unroll
                for (int ns = 0; ns < 4; ++ns)
                    sacc[ig][ns] = (f32x4){0.f, 0.f, 0.f, 0.f};
            #pragma unroll
            for (int m = 0; m < 20; ++m) {
                s16x8 f = *(const s16x8*)(kbuf + 32 * m);
                {
                    int kk = m & 3, ns = m >> 2;
                    if (ns < 4) {
                        sacc[0][ns] = mfma16(qf[0][kk], f, sacc[0][ns]);
                        sacc[1][ns] = mfma16(qf[1][kk], f, sacc[1][ns]);
                    }
                }
                {
                    int kk = (m & 3) + 4, ns = (m >> 2) - 1;
                    if (ns >= 0) {
                        sacc[0][ns] = mfma16(qf[0][kk], f, sacc[0][ns]);
                        sacc[1][ns] = mfma16(qf[1][kk], f, sacc[1][ns]);
                    }
                }
            }

            // bias + strict mask + fixed-max exp; P -> per-wave LDS
            const int J0 = jt * 64;
            int jv[4];
            #pragma unroll
            for (int ns = 0; ns < 4; ++ns) jv[ns] = J0 + 16 * ns + li;
            #pragma unroll
            for (int ig = 0; ig < 2; ++ig) {
                #pragma unroll
                for (int reg = 0; reg < 4; ++reg) {
                    const int i = I0 + 32 * rw + 16 * ig + 4 * lo4 + reg;
                    const float bi = binv[ig][reg];
                    #pragma unroll
                    for (int ns = 0; ns < 4; ++ns) {
                        float s = fmaf(sacc[ig][ns][reg], SCALE_, (float)jv[ns] * bi);
                        float p = (jv[ns] < i) ? __expf(s - MFIX_) : 0.0f;
                        lsum[ig][reg] += p;
                        psw[(ig * 16 + 4 * lo4 + reg) * 72 + 16 * ns + li] = f2bf(p);
                    }
                }
            }

            // PV: P from per-wave LDS, V^T direct from global (L2-resident)
            #pragma unroll
            for (int ig = 0; ig < 2; ++ig) {
                #pragma unroll
                for (int kk2 = 0; kk2 < 2; ++kk2) {
                    s16x8 pa = *(const s16x8*)&psw[(ig * 16 + li) * 72 + 32 * kk2 + 8 * lo4];
                    s16x8 pb = *(const s16x8*)(vtp + J0 + 32 * kk2);
                    O[ig] = mfma16(pa, pb, O[ig]);
                }
            }
        }

        if (do_stage)
            *(s16x8*)&ks[g][cb ^ 1][tloc * 8] = stg;

        __syncthreads();
    }

    // publish partials (plain-sum merge: fixed max => no rescale)
    #pragma unroll
    for (int ig = 0; ig < 2; ++ig) {
        #pragma unroll
        for (int reg = 0; reg < 4; ++reg) {
            float l = lsum[ig][reg];
            l += __shfl_xor(l, 1);
            l += __shfl_xor(l, 2);
            l += __shfl_xor(l, 4);
            l += __shfl_xor(l, 8);
            Om[w][ig][4 * lo4 + reg][li] = O[ig][reg];
            if (li == 0) lv[w][ig][4 * lo4 + reg] = l;
        }
    }
    __syncthreads();

    if (g == 0) {                                      // w in {0,1}; partner is w+2
        const int hc = h * VB_ + li;
        const float e0 = vemb0[hc], e1 = vemb1[hc];
        #pragma unroll
        for (int ig = 0; ig < 2; ++ig) {
            #pragma unroll
            for (int reg = 0; reg < 4; ++reg) {
                const int row = 4 * lo4 + reg;
                float Oc = Om[w][ig][row][li] + Om[w + 2][ig][row][li];
                float lc = lv[w][ig][row] + lv[w + 2][ig][row];
                float lr = fmaxf(lc, 1e-30f);
                float rinv = __builtin_amdgcn_rcpf(lr);
                rinv = rinv * (2.f - lr * rinv);
                float o = Oc * rinv;
                const int s = I0 + 32 * rw + 16 * ig + row;
                AO[(b * S_ + s) * HVB_ + hc] = f2bf(e0 + o * (e1 - e0));
            }
        }
    }
}

// ------------------------------------------------- K3: AO(bf16) @ Wo^T(bf16), no LDS
// grid 1024 = 256 row-tiles x 4 col-groups; block 256 (4 waves), wave owns 2 frags
__global__ __launch_bounds__(256) void k3_out(
    const u16* __restrict__ AO, const u16* __restrict__ Wob,
    float* __restrict__ out)
{
    const int tid = threadIdx.x;
    const int r0 = (blockIdx.x >> 2) * 16;
    const int cg = blockIdx.x & 3;
    const int wv = tid >> 6, lane = tid & 63;
    const int li = lane & 15, lo4 = lane >> 4;

    const u16* arow = AO + (r0 + li) * HVB_;

    f32x4 acc[2];
    acc[0] = (f32x4){0.f, 0.f, 0.f, 0.f};
    acc[1] = (f32x4){0.f, 0.f, 0.f, 0.f};

    #pragma unroll
    for (int kc = 0; kc < 4; ++kc) {
        s16x8 a = *(const s16x8*)&arow[32 * kc + 8 * lo4];
        #pragma unroll
        for (int u = 0; u < 2; ++u) {
            int o = cg * 128 + (wv + 4 * u) * 16 + li;
            s16x8 bfr = *(const s16x8*)&Wob[o * HVB_ + 32 * kc + 8 * lo4];
            acc[u] = mfma16(a, bfr, acc[u]);
        }
    }

    #pragma unroll
    for (int u = 0; u < 2; ++u) {
        int o = cg * 128 + (wv + 4 * u) * 16 + li;
        #pragma unroll
        for (int reg = 0; reg < 4; ++reg)
            out[(r0 + 4 * lo4 + reg) * HID_ + o] = acc[u][reg];
    }
}

// ------------------------------------------------- launch
extern "C" void kernel_launch(void* const* d_in, const int* in_sizes, int n_in,
                              void* d_out, int out_size, void* d_ws, size_t ws_size,
                              hipStream_t stream)
{
    (void)in_sizes; (void)n_in; (void)out_size;
    const float* hidden = (const float*)d_in[0];
    const float* Wq = (const float*)d_in[1];
    const float* Wk = (const float*)d_in[2];
    const float* Wv = (const float*)d_in[3];
    const float* Wo = (const float*)d_in[4];
    const float* ve0 = (const float*)d_in[5];
    const float* ve1 = (const float*)d_in[6];
    float* out = (float*)d_out;

    char* base = (char*)d_ws;
    u16* qb  = (u16*)(base);                        // [B,H,S,8]      524288 B
    u16* kb  = (u16*)(base + 524288);               // [B,HKV,S,8]    131072 B
    u16* vt  = (u16*)(base + 655360);               // [B,HKV,16,S]   262144 B (shifted, transposed)
    u16* AO  = (u16*)(base + 917504);               // [B*S,128] bf16 1048576 B
    u16* Wc  = (u16*)(base + 1966080);              // [128,512] bf16  131072 B (padded)
    u16* Wob = (u16*)(base + 2097152);              // [512,128] bf16  131072 B -> end 2228224
    if (ws_size < 2228224) return;

    hipLaunchKernelGGL(k0_convert, dim3(256), dim3(256), 0, stream,
                       Wq, Wk, Wv, Wo, Wc, Wob);
    hipLaunchKernelGGL(k1_proj, dim3(256), dim3(256), 0, stream,
                       hidden, Wc, qb, kb, vt);
    hipLaunchKernelGGL(k2_attn, dim3(512), dim3(256), 0, stream,
                       qb, kb, vt, ve0, ve1, AO);
    hipLaunchKernelGGL(k3_out, dim3(1024), dim3(256), 0, stream,
                       AO, Wob, out);
}